// Round 15
// baseline (1622.606 us; speedup 1.0000x reference)
//
#include <hip/hip_runtime.h>
#include <hip/hip_fp16.h>

#define NN 100000
#define NE 1600000
#define FIN 64
#define HID 128
#define NL 4
#define NG 512
#define FFN 300
#define BN_EPS 1e-5f
#define LDH 136   // padded LDS stride in halves
#define NB 512    // CSR buckets
#define NPB 196   // nodes per bucket
#define CURPAD 16
#define NCH 8     // feature chunks; chunk slab = NN*16*2B = 3.2 MB < 4 MB L2
#define CH 16

static inline size_t alignup(size_t x) { return (x + 255) & ~(size_t)255; }

struct half8 { __half2 h[4]; };   // 16 B

typedef _Float16 f16;
typedef __attribute__((ext_vector_type(4))) _Float16 f16x4;
typedef __attribute__((ext_vector_type(8))) _Float16 f16x8;
typedef __attribute__((ext_vector_type(4))) float f32x4;

// ======================= CSR build (bucketed, dense writes) =======================
__global__ __launch_bounds__(1024) void k_bcount(const int* __restrict__ col,
                                                 int* __restrict__ bcnt) {
    __shared__ int h[NB];
    int t = threadIdx.x;
    if (t < NB) h[t] = 0;
    __syncthreads();
    for (int e = blockIdx.x * 1024 + t; e < NE; e += 256 * 1024)
        atomicAdd(&h[col[e] / NPB], 1);
    __syncthreads();
    if (t < NB && h[t] > 0) atomicAdd(&bcnt[t], h[t]);
}

__global__ void k_bscan(const int* __restrict__ bcnt, int* __restrict__ bbase,
                        int* __restrict__ bcur) {
    __shared__ int s[NB];
    int t = threadIdx.x;  // NB threads
    int v = bcnt[t];
    s[t] = v;
    __syncthreads();
    for (int off = 1; off < NB; off <<= 1) {
        int u = (t >= off) ? s[t - off] : 0;
        __syncthreads();
        s[t] += u;
        __syncthreads();
    }
    int excl = s[t] - v;
    bbase[t] = excl;
    bcur[t * CURPAD] = excl;
    if (t == NB - 1) bbase[NB] = s[t];
}

__global__ __launch_bounds__(1024) void k_bscatter2(const int* __restrict__ row,
                                                    const int* __restrict__ col,
                                                    int* __restrict__ bcur,
                                                    int* __restrict__ ebuf) {
    __shared__ int hcnt[NB];
    __shared__ int hbase[NB];
    int t = threadIdx.x;
    int e0 = blockIdx.x * 4096;
    if (t < NB) hcnt[t] = 0;
    __syncthreads();
    #pragma unroll
    for (int k = 0; k < 4; ++k) {
        int e = e0 + k * 1024 + t;
        if (e < NE) atomicAdd(&hcnt[col[e] / NPB], 1);
    }
    __syncthreads();
    if (t < NB) {
        int c = hcnt[t];
        hbase[t] = (c > 0) ? atomicAdd(&bcur[t * CURPAD], c) : 0;
    }
    __syncthreads();
    if (t < NB) hcnt[t] = 0;
    __syncthreads();
    #pragma unroll
    for (int k = 0; k < 4; ++k) {
        int e = e0 + k * 1024 + t;
        if (e < NE) {
            int c = col[e];
            int b = c / NPB;
            int loc = atomicAdd(&hcnt[b], 1);
            ebuf[hbase[b] + loc] = row[e] | ((c - b * NPB) << 17);
        }
    }
}

__global__ __launch_bounds__(256) void k_binfill(const int* __restrict__ ebuf,
                                                 const int* __restrict__ bbase,
                                                 int* __restrict__ offs,
                                                 int* __restrict__ ends,
                                                 float* __restrict__ dinv,
                                                 int* __restrict__ csr_src) {
    __shared__ int cnt[NPB];
    __shared__ int scn[256];
    __shared__ int cur[NPB];
    int b = blockIdx.x, t = threadIdx.x;
    int lo = b * NPB;
    int hi = lo + NPB; if (hi > NN) hi = NN;
    int n = hi - lo;
    if (n <= 0) return;
    int s0 = bbase[b], s1 = bbase[b + 1];
    for (int i = t; i < NPB; i += 256) cnt[i] = 0;
    __syncthreads();
    for (int j = s0 + t; j < s1; j += 256)
        atomicAdd(&cnt[((unsigned)ebuf[j]) >> 17], 1);
    __syncthreads();
    int v = (t < n) ? cnt[t] : 0;
    scn[t] = v;
    __syncthreads();
    for (int off = 1; off < 256; off <<= 1) {
        int u = (t >= off) ? scn[t - off] : 0;
        __syncthreads();
        scn[t] += u;
        __syncthreads();
    }
    if (t < n) {
        int g = s0 + scn[t] - v;
        offs[lo + t] = g;
        ends[lo + t] = g + v;
        dinv[lo + t] = rsqrtf((float)(v + 1));
        cur[t] = g;
    }
    __syncthreads();
    for (int j = s0 + t; j < s1; j += 256) {
        int e = ebuf[j];
        int pos = atomicAdd(&cur[((unsigned)e) >> 17], 1);
        csr_src[pos] = e & 0x1FFFF;
    }
}

// ==== W preconvert: wt[l][c][k] = (f16)Ws[l][k][c]; wte[c][k] = (f16)encW[k][c] ====
__global__ void k_convW(const float* __restrict__ Ws, const float* __restrict__ encW,
                        f16* __restrict__ wt, f16* __restrict__ wte) {
    int tid = blockIdx.x * 256 + threadIdx.x;
    for (int i = tid; i < NL * HID * HID; i += 64 * 256) {
        int l = i >> 14, rem = i & 16383;
        int c = rem >> 7, k = rem & 127;
        wt[i] = (f16)Ws[(l << 14) + k * HID + c];
    }
    for (int i = tid; i < HID * FIN; i += 64 * 256) {
        int c = i >> 6, k = i & 63;
        wte[i] = (f16)encW[k * HID + c];
    }
}

// ======== MFMA encoder: hc[ct][row][16] = (x[N,64] @ encW) + b -> f16 chunked ========
__global__ __launch_bounds__(256) void k_enc_mfma(const float* __restrict__ x,
                                                  const f16* __restrict__ wte,
                                                  const float* __restrict__ b,
                                                  __half* __restrict__ hc) {
    __shared__ f16 sx[64 * 72];
    __shared__ f16 sw[128 * 72];
    int t = threadIdx.x;
    int row0 = blockIdx.x * 64;
    for (int idx = t; idx < 64 * 16; idx += 256) {
        int r = idx >> 4, c4 = (idx & 15) * 4;
        float4 v = {0.0f, 0.0f, 0.0f, 0.0f};
        if (row0 + r < NN) v = *(const float4*)(x + (size_t)(row0 + r) * FIN + c4);
        f16x4 o = {(f16)v.x, (f16)v.y, (f16)v.z, (f16)v.w};
        *(f16x4*)&sx[r * 72 + c4] = o;
    }
    for (int idx = t; idx < 128 * 8; idx += 256) {
        int c = idx >> 3, ch = (idx & 7) * 8;
        *(f16x8*)&sw[c * 72 + ch] = *(const f16x8*)(wte + c * FIN + ch);
    }
    __syncthreads();
    int w = t >> 6, lane = t & 63;
    int lrow = lane & 15, lk = (lane >> 4) * 8;
    f32x4 acc[8];
    #pragma unroll
    for (int ct = 0; ct < 8; ++ct) acc[ct] = (f32x4){0.0f, 0.0f, 0.0f, 0.0f};
    const f16* pa = &sx[(w * 16 + lrow) * 72 + lk];
    #pragma unroll
    for (int ks = 0; ks < 2; ++ks) {
        f16x8 a = *(const f16x8*)(pa + ks * 32);
        #pragma unroll
        for (int ct = 0; ct < 8; ++ct) {
            f16x8 bb = *(const f16x8*)&sw[(ct * 16 + lrow) * 72 + ks * 32 + lk];
            acc[ct] = __builtin_amdgcn_mfma_f32_16x16x32_f16(a, bb, acc[ct], 0, 0, 0);
        }
    }
    float bv[8];
    #pragma unroll
    for (int ct = 0; ct < 8; ++ct) bv[ct] = b[ct * 16 + lrow];
    int rbase = row0 + w * 16 + (lane >> 4) * 4;
    #pragma unroll
    for (int i = 0; i < 4; ++i) {
        int grow = rbase + i;
        if (grow < NN) {
            #pragma unroll
            for (int ct = 0; ct < 8; ++ct)
                hc[((size_t)ct * NN + grow) * CH + lrow] = __float2half(acc[ct][i] + bv[ct]);
        }
    }
}

// ==== MFMA layer GEMM: chunked in, chunked out; hw = dinv[row]*(h @ W) ====
__global__ __launch_bounds__(256) void k_gemm_mfma(const __half* __restrict__ hcin,
                                                   const f16* __restrict__ wt,
                                                   const float* __restrict__ dinv,
                                                   __half* __restrict__ hwc) {
    __shared__ f16 sh[64 * LDH];
    __shared__ f16 sw[128 * LDH];
    int t = threadIdx.x;
    int row0 = blockIdx.x * 64;
    // stage 64 rows x 128 features from chunked layout [c][node][16]
    for (int idx = t; idx < 1024; idx += 256) {
        int cc = idx >> 7;          // chunk
        int l = idx & 127;
        int r = l >> 1, half = l & 1;
        f16x8 v = {0, 0, 0, 0, 0, 0, 0, 0};
        if (row0 + r < NN)
            v = *(const f16x8*)(hcin + ((size_t)cc * NN + row0 + r) * CH + half * 8);
        *(f16x8*)&sh[r * LDH + cc * 16 + half * 8] = v;
    }
    for (int idx = t; idx < 128 * 16; idx += 256) {
        int c = idx >> 4, ch = (idx & 15) * 8;
        *(f16x8*)&sw[c * LDH + ch] = *(const f16x8*)(wt + c * HID + ch);
    }
    __syncthreads();
    int w = t >> 6, lane = t & 63;
    int lrow = lane & 15, lk = (lane >> 4) * 8;
    f32x4 acc[8];
    #pragma unroll
    for (int ct = 0; ct < 8; ++ct) acc[ct] = (f32x4){0.0f, 0.0f, 0.0f, 0.0f};
    const f16* pa = &sh[(w * 16 + lrow) * LDH + lk];
    #pragma unroll
    for (int ks = 0; ks < 4; ++ks) {
        f16x8 a = *(const f16x8*)(pa + ks * 32);
        #pragma unroll
        for (int ct = 0; ct < 8; ++ct) {
            f16x8 b = *(const f16x8*)&sw[(ct * 16 + lrow) * LDH + ks * 32 + lk];
            acc[ct] = __builtin_amdgcn_mfma_f32_16x16x32_f16(a, b, acc[ct], 0, 0, 0);
        }
    }
    int rbase = row0 + w * 16 + (lane >> 4) * 4;
    #pragma unroll
    for (int i = 0; i < 4; ++i) {
        int grow = rbase + i;
        if (grow < NN) {
            float dv = dinv[grow];
            #pragma unroll
            for (int ct = 0; ct < 8; ++ct)
                hwc[((size_t)ct * NN + grow) * CH + lrow] = __float2half(dv * acc[ct][i]);
        }
    }
}

// == XCD-pinned chunked gather v2: chunk = bid&7 -> own XCD; 3.2 MB slab L2-resident.
//    Wave per node: 32 edge-slots x 2 lanes x 16B = one 32B chunk row per 2 lanes,
//    32 edges per load instruction (same instr count as row-major gather). ==
__device__ __forceinline__ void add8(float* a, float4 raw) {
    const __half2* p = (const __half2*)&raw;
    #pragma unroll
    for (int q = 0; q < 4; ++q) {
        float2 u = __half22float2(p[q]);
        a[2 * q] += u.x;
        a[2 * q + 1] += u.y;
    }
}

__global__ __launch_bounds__(256) void k_gather_c8(
    const int* __restrict__ offs, const int* __restrict__ ends,
    const int* __restrict__ csr_src,
    const float* __restrict__ dinv,
    const __half* __restrict__ hwc, const __half* __restrict__ hprevc,
    const float* __restrict__ bias, const float* __restrict__ gamma,
    const float* __restrict__ beta, const float* __restrict__ mean,
    const float* __restrict__ var,
    __half* __restrict__ houtc, int with_res) {
    int bid = blockIdx.x;
    int c = bid & 7;                  // chunk == XCD (round-robin dispatch)
    int node = (bid >> 3) * 4 + (threadIdx.x >> 6);
    if (node >= NN) return;
    int lane = threadIdx.x & 63;
    int slot = lane >> 1;             // 32 edge slots
    int h = lane & 1;                 // row half (16 B each)
    const __half* slab = hwc + (size_t)c * NN * CH;
    int s = offs[node], e = ends[node];
    float a[8] = {0, 0, 0, 0, 0, 0, 0, 0};
    int j = s + slot;
    for (; j + 32 < e; j += 64) {     // long-degree tier: 64 edges in flight
        int s0 = csr_src[j], s1 = csr_src[j + 32];
        float4 r0 = *(const float4*)(slab + (size_t)s0 * CH + h * 8);
        float4 r1 = *(const float4*)(slab + (size_t)s1 * CH + h * 8);
        add8(a, r0);
        add8(a, r1);
    }
    if (j < e) {
        int s0 = csr_src[j];
        float4 r0 = *(const float4*)(slab + (size_t)s0 * CH + h * 8);
        add8(a, r0);
    }
    // reduce over 32 slots (lane bits 1..5)
    #pragma unroll
    for (int q = 0; q < 8; ++q) {
        a[q] += __shfl_xor(a[q], 2);
        a[q] += __shfl_xor(a[q], 4);
        a[q] += __shfl_xor(a[q], 8);
        a[q] += __shfl_xor(a[q], 16);
        a[q] += __shfl_xor(a[q], 32);
    }
    if (slot) return;                 // lanes 0,1 continue
    // self-loop (pre-scaled row) then final dinv scale
    float4 sraw = *(const float4*)(slab + (size_t)node * CH + h * 8);
    add8(a, sraw);
    float dc = dinv[node];
    int f0 = c * CH + h * 8;          // global feature base for this lane's 8 features
    float4 bi0 = *(const float4*)(bias + f0),  bi1 = *(const float4*)(bias + f0 + 4);
    float4 mn0 = *(const float4*)(mean + f0),  mn1 = *(const float4*)(mean + f0 + 4);
    float4 vr0 = *(const float4*)(var + f0),   vr1 = *(const float4*)(var + f0 + 4);
    float4 gm0 = *(const float4*)(gamma + f0), gm1 = *(const float4*)(gamma + f0 + 4);
    float4 bt0 = *(const float4*)(beta + f0),  bt1 = *(const float4*)(beta + f0 + 4);
    float bi[8] = {bi0.x, bi0.y, bi0.z, bi0.w, bi1.x, bi1.y, bi1.z, bi1.w};
    float mn[8] = {mn0.x, mn0.y, mn0.z, mn0.w, mn1.x, mn1.y, mn1.z, mn1.w};
    float vr[8] = {vr0.x, vr0.y, vr0.z, vr0.w, vr1.x, vr1.y, vr1.z, vr1.w};
    float gm[8] = {gm0.x, gm0.y, gm0.z, gm0.w, gm1.x, gm1.y, gm1.z, gm1.w};
    float bt[8] = {bt0.x, bt0.y, bt0.z, bt0.w, bt1.x, bt1.y, bt1.z, bt1.w};
    float o[8];
    #pragma unroll
    for (int q = 0; q < 8; ++q)
        o[q] = fmaxf((dc * a[q] + bi[q] - mn[q]) * rsqrtf(vr[q] + BN_EPS) * gm[q] + bt[q], 0.0f);
    if (with_res) {
        float4 praw = *(const float4*)(hprevc + ((size_t)c * NN + node) * CH + h * 8);
        const __half2* pp = (const __half2*)&praw;
        #pragma unroll
        for (int q = 0; q < 4; ++q) {
            float2 p = __half22float2(pp[q]);
            o[2 * q] += p.x;
            o[2 * q + 1] += p.y;
        }
    }
    half8 ov;
    #pragma unroll
    for (int q = 0; q < 4; ++q)
        ov.h[q] = __floats2half2_rn(o[2 * q], o[2 * q + 1]);
    *(half8*)(houtc + ((size_t)c * NN + node) * CH + h * 8) = ov;
}

// ======================= pool (segmented, chunked input) =======================
__device__ __forceinline__ int lower_bound_dev(const int* __restrict__ a, int n, int v) {
    int lo = 0, hi = n;
    while (lo < hi) {
        int m = (lo + hi) >> 1;
        if (a[m] < v) lo = m + 1; else hi = m;
    }
    return lo;
}

__global__ __launch_bounds__(256) void k_pool_seg(const __half* __restrict__ hc,
                                                  const int* __restrict__ batch,
                                                  float* __restrict__ gfeat) {
    __shared__ int range[2];
    __shared__ float s[256];
    int g = blockIdx.x, t = threadIdx.x;
    if (t == 0) {
        range[0] = lower_bound_dev(batch, NN, g);
        range[1] = lower_bound_dev(batch, NN, g + 1);
    }
    __syncthreads();
    int start = range[0], end = range[1];
    int f = t & 127, half = t >> 7;
    int cf = f >> 4, fl = f & 15;
    const __half* slab = hc + (size_t)cf * NN * CH;
    float acc = 0.0f;
    for (int i = start + half; i < end; i += 2)
        acc += __half2float(slab[(size_t)i * CH + fl]);
    s[t] = acc;
    __syncthreads();
    if (t < 128) {
        float sum = s[t] + s[t + 128];
        float cnt = (float)(end - start);
        gfeat[(size_t)g * HID + t] = sum / fmaxf(cnt, 1.0f);
    }
}

// ======================= MLP =======================
__global__ void k_mlp0(const float* __restrict__ gfeat,
                       const float* __restrict__ W, const float* __restrict__ b,
                       float* __restrict__ out) {
    __shared__ float srow[HID];
    int g = blockIdx.x, t = threadIdx.x;  // 128 threads
    if (t < HID) srow[t] = gfeat[(size_t)g * HID + t];
    __syncthreads();
    for (int j = t; j < FFN; j += 128) {
        float acc = b[j];
        for (int k = 0; k < HID; ++k) acc += srow[k] * W[k * FFN + j];
        out[(size_t)g * FFN + j] = fmaxf(acc, 0.0f);
    }
}

__global__ void k_mlp1(const float* __restrict__ in, const float* __restrict__ W,
                       const float* __restrict__ b, float* __restrict__ out) {
    __shared__ float srow[FFN];
    int g = blockIdx.x, t = threadIdx.x;  // 128 threads
    for (int k = t; k < FFN; k += 128) srow[k] = in[(size_t)g * FFN + k];
    __syncthreads();
    for (int j = t; j < FFN; j += 128) {
        float acc = b[j];
        for (int k = 0; k < FFN; ++k) acc += srow[k] * W[k * FFN + j];
        out[(size_t)g * FFN + j] = fmaxf(acc, 0.0f);
    }
}

__global__ void k_mlp2(const float* __restrict__ in, const float* __restrict__ W,
                       const float* __restrict__ b, float* __restrict__ out) {
    int g = blockIdx.x, lane = threadIdx.x;  // 64 threads
    float acc = 0.0f;
    for (int k = lane; k < FFN; k += 64) acc += in[(size_t)g * FFN + k] * W[k];
    for (int off = 32; off > 0; off >>= 1) acc += __shfl_down(acc, off);
    if (lane == 0) out[g] = acc + b[0];
}

extern "C" void kernel_launch(void* const* d_in, const int* in_sizes, int n_in,
                              void* d_out, int out_size, void* d_ws, size_t ws_size,
                              hipStream_t stream) {
    const float* x    = (const float*)d_in[0];
    const int*   ei   = (const int*)d_in[1];    // [2,E]: rows then cols
    const int*   batch= (const int*)d_in[2];
    const float* encW = (const float*)d_in[3];
    const float* encb = (const float*)d_in[4];
    const float* Ws   = (const float*)d_in[5];
    const float* bs   = (const float*)d_in[6];
    const float* gam  = (const float*)d_in[7];
    const float* bet  = (const float*)d_in[8];
    const float* mean = (const float*)d_in[9];
    const float* var  = (const float*)d_in[10];
    const float* W0   = (const float*)d_in[11];
    const float* b0   = (const float*)d_in[12];
    const float* W1   = (const float*)d_in[13];
    const float* b1   = (const float*)d_in[14];
    const float* W2   = (const float*)d_in[15];
    const float* b2   = (const float*)d_in[16];
    float* out = (float*)d_out;

    char* w = (char*)d_ws;
    float*  dinv    = (float*)w;  w += alignup((size_t)NN * 4);
    int*    offs    = (int*)w;    w += alignup((size_t)NN * 4);
    int*    ends    = (int*)w;    w += alignup((size_t)NN * 4);
    int*    csr_src = (int*)w;    w += alignup((size_t)NE * 4);
    int*    bcnt    = (int*)w;    w += alignup((size_t)NB * 4);
    int*    bbase   = (int*)w;    w += alignup((size_t)(NB + 1) * 4);
    int*    bcur    = (int*)w;    w += alignup((size_t)NB * CURPAD * 4);
    int*    ebuf    = (int*)w;    w += alignup((size_t)NE * 4);
    __half* hA      = (__half*)w; w += alignup((size_t)NN * HID * 2);
    __half* hB      = (__half*)w; w += alignup((size_t)NN * HID * 2);
    __half* hw_     = (__half*)w; w += alignup((size_t)NN * HID * 2);
    f16*    wt      = (f16*)w;    w += alignup((size_t)NL * HID * HID * 2);
    f16*    wte     = (f16*)w;    w += alignup((size_t)HID * FIN * 2);
    float*  gfeat   = (float*)w;  w += alignup((size_t)NG * HID * 4);
    float*  m0      = (float*)w;  w += alignup((size_t)NG * FFN * 4);
    float*  m1      = (float*)w;  w += alignup((size_t)NG * FFN * 4);

    const int* row = ei;
    const int* col = ei + NE;

    // ---- CSR build ----
    hipMemsetAsync(bcnt, 0, (size_t)NB * 4, stream);
    k_bcount<<<256, 1024, 0, stream>>>(col, bcnt);
    k_bscan<<<1, NB, 0, stream>>>(bcnt, bbase, bcur);
    k_bscatter2<<<(NE + 4095) / 4096, 1024, 0, stream>>>(row, col, bcur, ebuf);
    k_binfill<<<NB, 256, 0, stream>>>(ebuf, bbase, offs, ends, dinv, csr_src);

    // ---- weights preconvert + encoder (MFMA, chunked out) ----
    k_convW<<<64, 256, 0, stream>>>(Ws, encW, wt, wte);
    k_enc_mfma<<<(NN + 63) / 64, 256, 0, stream>>>(x, wte, encb, hA);

    __half* hcur = hA;
    __half* hnext = hB;
    for (int l = 0; l < NL; ++l) {
        k_gemm_mfma<<<(NN + 63) / 64, 256, 0, stream>>>(hcur, wt + (size_t)l * HID * HID, dinv, hw_);
        k_gather_c8<<<((NN + 3) / 4) * NCH, 256, 0, stream>>>(
            offs, ends, csr_src, dinv, hw_, hcur,
            bs + l * HID, gam + l * HID, bet + l * HID, mean + l * HID, var + l * HID,
            hnext, l > 0 ? 1 : 0);
        __half* tmp = hcur; hcur = hnext; hnext = tmp;
    }

    // ---- pool + MLP ----
    k_pool_seg<<<NG, 256, 0, stream>>>(hcur, batch, gfeat);
    k_mlp0<<<NG, 128, 0, stream>>>(gfeat, W0, b0, m0);
    k_mlp1<<<NG, 128, 0, stream>>>(m0, W1, b1, m1);
    k_mlp2<<<NG, 64, 0, stream>>>(m1, W2, b2, out);
}

// Round 16
// 523.846 us; speedup vs baseline: 3.0975x; 3.0975x over previous
//
#include <hip/hip_runtime.h>
#include <hip/hip_fp16.h>

#define NN 100000
#define NE 1600000
#define FIN 64
#define HID 128
#define NL 4
#define NG 512
#define FFN 300
#define BN_EPS 1e-5f
#define LDH 136   // padded LDS stride in halves
#define NB 512    // CSR buckets
#define NPB 196   // nodes per bucket; fits 8 bits for packing
#define CURPAD 16 // bucket cursor padding (one per 64B line)

static inline size_t alignup(size_t x) { return (x + 255) & ~(size_t)255; }

struct half8 { __half2 h[4]; };   // 16 B

typedef _Float16 f16;
typedef __attribute__((ext_vector_type(4))) _Float16 f16x4;
typedef __attribute__((ext_vector_type(8))) _Float16 f16x8;
typedef __attribute__((ext_vector_type(4))) float f32x4;

// ======================= CSR build (bucketed, dense writes) =======================
__global__ __launch_bounds__(1024) void k_bcount(const int* __restrict__ col,
                                                 int* __restrict__ bcnt) {
    __shared__ int h[NB];
    int t = threadIdx.x;
    if (t < NB) h[t] = 0;
    __syncthreads();
    for (int e = blockIdx.x * 1024 + t; e < NE; e += 256 * 1024)
        atomicAdd(&h[col[e] / NPB], 1);
    __syncthreads();
    if (t < NB && h[t] > 0) atomicAdd(&bcnt[t], h[t]);
}

__global__ void k_bscan(const int* __restrict__ bcnt, int* __restrict__ bbase,
                        int* __restrict__ bcur) {
    __shared__ int s[NB];
    int t = threadIdx.x;  // NB threads
    int v = bcnt[t];
    s[t] = v;
    __syncthreads();
    for (int off = 1; off < NB; off <<= 1) {
        int u = (t >= off) ? s[t - off] : 0;
        __syncthreads();
        s[t] += u;
        __syncthreads();
    }
    int excl = s[t] - v;
    bbase[t] = excl;
    bcur[t * CURPAD] = excl;
    if (t == NB - 1) bbase[NB] = s[t];
}

// hierarchical scatter: block histograms 4096 edges in LDS, reserves per-bucket
// ranges with ONE global atomic per bucket per block, then scatters via LDS cursors.
__global__ __launch_bounds__(1024) void k_bscatter2(const int* __restrict__ row,
                                                    const int* __restrict__ col,
                                                    int* __restrict__ bcur,
                                                    int* __restrict__ ebuf) {
    __shared__ int hcnt[NB];
    __shared__ int hbase[NB];
    int t = threadIdx.x;
    int e0 = blockIdx.x * 4096;
    if (t < NB) hcnt[t] = 0;
    __syncthreads();
    #pragma unroll
    for (int k = 0; k < 4; ++k) {
        int e = e0 + k * 1024 + t;
        if (e < NE) atomicAdd(&hcnt[col[e] / NPB], 1);
    }
    __syncthreads();
    if (t < NB) {
        int c = hcnt[t];
        hbase[t] = (c > 0) ? atomicAdd(&bcur[t * CURPAD], c) : 0;
    }
    __syncthreads();
    if (t < NB) hcnt[t] = 0;
    __syncthreads();
    #pragma unroll
    for (int k = 0; k < 4; ++k) {
        int e = e0 + k * 1024 + t;
        if (e < NE) {
            int c = col[e];
            int b = c / NPB;
            int loc = atomicAdd(&hcnt[b], 1);
            ebuf[hbase[b] + loc] = row[e] | ((c - b * NPB) << 17);
        }
    }
}

__global__ __launch_bounds__(256) void k_binfill(const int* __restrict__ ebuf,
                                                 const int* __restrict__ bbase,
                                                 int* __restrict__ offs,
                                                 int* __restrict__ ends,
                                                 float* __restrict__ dinv,
                                                 int* __restrict__ csr_src) {
    __shared__ int cnt[NPB];
    __shared__ int scn[256];
    __shared__ int cur[NPB];
    int b = blockIdx.x, t = threadIdx.x;
    int lo = b * NPB;
    int hi = lo + NPB; if (hi > NN) hi = NN;
    int n = hi - lo;
    if (n <= 0) return;
    int s0 = bbase[b], s1 = bbase[b + 1];
    for (int i = t; i < NPB; i += 256) cnt[i] = 0;
    __syncthreads();
    for (int j = s0 + t; j < s1; j += 256)
        atomicAdd(&cnt[((unsigned)ebuf[j]) >> 17], 1);
    __syncthreads();
    int v = (t < n) ? cnt[t] : 0;
    scn[t] = v;
    __syncthreads();
    for (int off = 1; off < 256; off <<= 1) {
        int u = (t >= off) ? scn[t - off] : 0;
        __syncthreads();
        scn[t] += u;
        __syncthreads();
    }
    if (t < n) {
        int g = s0 + scn[t] - v;
        offs[lo + t] = g;
        ends[lo + t] = g + v;
        dinv[lo + t] = rsqrtf((float)(v + 1));
        cur[t] = g;
    }
    __syncthreads();
    for (int j = s0 + t; j < s1; j += 256) {
        int e = ebuf[j];
        int pos = atomicAdd(&cur[((unsigned)e) >> 17], 1);
        csr_src[pos] = e & 0x1FFFF;
    }
}

// ==== W preconvert: wt[l][c][k] = (f16)Ws[l][k][c]; wte[c][k] = (f16)encW[k][c] ====
__global__ void k_convW(const float* __restrict__ Ws, const float* __restrict__ encW,
                        f16* __restrict__ wt, f16* __restrict__ wte) {
    int tid = blockIdx.x * 256 + threadIdx.x;
    for (int i = tid; i < NL * HID * HID; i += 64 * 256) {
        int l = i >> 14, rem = i & 16383;
        int c = rem >> 7, k = rem & 127;
        wt[i] = (f16)Ws[(l << 14) + k * HID + c];
    }
    for (int i = tid; i < HID * FIN; i += 64 * 256) {
        int c = i >> 6, k = i & 63;
        wte[i] = (f16)encW[k * HID + c];
    }
}

// ======== MFMA encoder: h = (x[N,64](f32->f16) @ encW) + b -> f16 ========
__global__ __launch_bounds__(256) void k_enc_mfma(const float* __restrict__ x,
                                                  const f16* __restrict__ wte,
                                                  const float* __restrict__ b,
                                                  __half* __restrict__ h) {
    __shared__ f16 sx[64 * 72];    // 64 rows x 64 k, stride 72
    __shared__ f16 sw[128 * 72];   // 128 cols x 64 k
    int t = threadIdx.x;
    int row0 = blockIdx.x * 64;
    for (int idx = t; idx < 64 * 16; idx += 256) {
        int r = idx >> 4, c4 = (idx & 15) * 4;
        float4 v = {0.0f, 0.0f, 0.0f, 0.0f};
        if (row0 + r < NN) v = *(const float4*)(x + (size_t)(row0 + r) * FIN + c4);
        f16x4 o = {(f16)v.x, (f16)v.y, (f16)v.z, (f16)v.w};
        *(f16x4*)&sx[r * 72 + c4] = o;
    }
    for (int idx = t; idx < 128 * 8; idx += 256) {
        int c = idx >> 3, ch = (idx & 7) * 8;
        *(f16x8*)&sw[c * 72 + ch] = *(const f16x8*)(wte + c * FIN + ch);
    }
    __syncthreads();
    int w = t >> 6, lane = t & 63;
    int lrow = lane & 15, lk = (lane >> 4) * 8;
    f32x4 acc[8];
    #pragma unroll
    for (int ct = 0; ct < 8; ++ct) acc[ct] = (f32x4){0.0f, 0.0f, 0.0f, 0.0f};
    const f16* pa = &sx[(w * 16 + lrow) * 72 + lk];
    #pragma unroll
    for (int ks = 0; ks < 2; ++ks) {
        f16x8 a = *(const f16x8*)(pa + ks * 32);
        #pragma unroll
        for (int ct = 0; ct < 8; ++ct) {
            f16x8 bb = *(const f16x8*)&sw[(ct * 16 + lrow) * 72 + ks * 32 + lk];
            acc[ct] = __builtin_amdgcn_mfma_f32_16x16x32_f16(a, bb, acc[ct], 0, 0, 0);
        }
    }
    float bv[8];
    #pragma unroll
    for (int ct = 0; ct < 8; ++ct) bv[ct] = b[ct * 16 + lrow];
    int rbase = row0 + w * 16 + (lane >> 4) * 4;
    #pragma unroll
    for (int i = 0; i < 4; ++i) {
        int grow = rbase + i;
        if (grow < NN) {
            #pragma unroll
            for (int ct = 0; ct < 8; ++ct)
                h[(size_t)grow * HID + ct * 16 + lrow] = __float2half(acc[ct][i] + bv[ct]);
        }
    }
}

// ==== MFMA layer GEMM: hw = dinv[row] * (h[N,128](f16) @ W[128,128]) -> f16 row-major ====
__global__ __launch_bounds__(256) void k_gemm_mfma(const __half* __restrict__ h,
                                                   const f16* __restrict__ wt,
                                                   const float* __restrict__ dinv,
                                                   __half* __restrict__ hw) {
    __shared__ f16 sh[64 * LDH];
    __shared__ f16 sw[128 * LDH];
    int t = threadIdx.x;
    int row0 = blockIdx.x * 64;
    for (int idx = t; idx < 64 * 16; idx += 256) {
        int r = idx >> 4, ch = (idx & 15) * 8;
        f16x8 v = {0, 0, 0, 0, 0, 0, 0, 0};
        if (row0 + r < NN) v = *(const f16x8*)(h + (size_t)(row0 + r) * HID + ch);
        *(f16x8*)&sh[r * LDH + ch] = v;
    }
    for (int idx = t; idx < 128 * 16; idx += 256) {
        int c = idx >> 4, ch = (idx & 15) * 8;
        *(f16x8*)&sw[c * LDH + ch] = *(const f16x8*)(wt + c * HID + ch);
    }
    __syncthreads();
    int w = t >> 6, lane = t & 63;
    int lrow = lane & 15, lk = (lane >> 4) * 8;
    f32x4 acc[8];
    #pragma unroll
    for (int ct = 0; ct < 8; ++ct) acc[ct] = (f32x4){0.0f, 0.0f, 0.0f, 0.0f};
    const f16* pa = &sh[(w * 16 + lrow) * LDH + lk];
    #pragma unroll
    for (int ks = 0; ks < 4; ++ks) {
        f16x8 a = *(const f16x8*)(pa + ks * 32);
        #pragma unroll
        for (int ct = 0; ct < 8; ++ct) {
            f16x8 b = *(const f16x8*)&sw[(ct * 16 + lrow) * LDH + ks * 32 + lk];
            acc[ct] = __builtin_amdgcn_mfma_f32_16x16x32_f16(a, b, acc[ct], 0, 0, 0);
        }
    }
    int rbase = row0 + w * 16 + (lane >> 4) * 4;
    #pragma unroll
    for (int i = 0; i < 4; ++i) {
        int grow = rbase + i;
        if (grow < NN) {
            float dv = dinv[grow];
            #pragma unroll
            for (int ct = 0; ct < 8; ++ct)
                hw[(size_t)grow * HID + ct * 16 + lrow] = __float2half(dv * acc[ct][i]);
        }
    }
}

// == fused gather: wave per node; 16 lanes x 16B span the 256B row; 4 edge
//    groups; up to 4 loads (16 edges, 64 lines) in flight per wave. ==
__device__ __forceinline__ void add8(float* a, float4 raw) {
    const __half2* p = (const __half2*)&raw;
    #pragma unroll
    for (int q = 0; q < 4; ++q) {
        float2 u = __half22float2(p[q]);
        a[2 * q] += u.x;
        a[2 * q + 1] += u.y;
    }
}

__global__ __launch_bounds__(256) void k_gather(
    const int* __restrict__ offs, const int* __restrict__ ends,
    const int* __restrict__ csr_src,
    const float* __restrict__ dinv,
    const __half* __restrict__ hw, const __half* __restrict__ hprev,
    const float* __restrict__ bias, const float* __restrict__ gamma,
    const float* __restrict__ beta, const float* __restrict__ mean,
    const float* __restrict__ var,
    __half* __restrict__ hout, int with_res) {
    int node = (blockIdx.x * 256 + threadIdx.x) >> 6;
    if (node >= NN) return;
    int lane = threadIdx.x & 63;
    int grp = lane >> 4;      // edge group (4 per wave)
    int fb = (lane & 15) * 8; // first of this lane's 8 features (16 B)
    int s = offs[node], e = ends[node];
    float a[8] = {0, 0, 0, 0, 0, 0, 0, 0};
    int j = s + grp;
    for (; j + 12 < e; j += 16) {  // 4 loads/group -> 16 edges, 64 lines in flight
        int s0 = csr_src[j], s1 = csr_src[j + 4], s2 = csr_src[j + 8], s3 = csr_src[j + 12];
        float4 r0 = *(const float4*)(hw + (size_t)s0 * HID + fb);
        float4 r1 = *(const float4*)(hw + (size_t)s1 * HID + fb);
        float4 r2 = *(const float4*)(hw + (size_t)s2 * HID + fb);
        float4 r3 = *(const float4*)(hw + (size_t)s3 * HID + fb);
        add8(a, r0); add8(a, r1); add8(a, r2); add8(a, r3);
    }
    for (; j + 4 < e; j += 8) {
        int s0 = csr_src[j], s1 = csr_src[j + 4];
        float4 r0 = *(const float4*)(hw + (size_t)s0 * HID + fb);
        float4 r1 = *(const float4*)(hw + (size_t)s1 * HID + fb);
        add8(a, r0); add8(a, r1);
    }
    for (; j < e; j += 4) {
        int s0 = csr_src[j];
        float4 r0 = *(const float4*)(hw + (size_t)s0 * HID + fb);
        add8(a, r0);
    }
    // combine the 4 edge groups
    #pragma unroll
    for (int q = 0; q < 8; ++q) {
        a[q] += __shfl_xor(a[q], 16);
        a[q] += __shfl_xor(a[q], 32);
    }
    if (grp) return;
    // self-loop (pre-scaled row) then final dinv[c] scale
    float4 sraw = *(const float4*)(hw + (size_t)node * HID + fb);
    add8(a, sraw);
    float dc = dinv[node];
    float4 bi0 = *(const float4*)(bias + fb),  bi1 = *(const float4*)(bias + fb + 4);
    float4 mn0 = *(const float4*)(mean + fb),  mn1 = *(const float4*)(mean + fb + 4);
    float4 vr0 = *(const float4*)(var + fb),   vr1 = *(const float4*)(var + fb + 4);
    float4 gm0 = *(const float4*)(gamma + fb), gm1 = *(const float4*)(gamma + fb + 4);
    float4 bt0 = *(const float4*)(beta + fb),  bt1 = *(const float4*)(beta + fb + 4);
    float bi[8] = {bi0.x, bi0.y, bi0.z, bi0.w, bi1.x, bi1.y, bi1.z, bi1.w};
    float mn[8] = {mn0.x, mn0.y, mn0.z, mn0.w, mn1.x, mn1.y, mn1.z, mn1.w};
    float vr[8] = {vr0.x, vr0.y, vr0.z, vr0.w, vr1.x, vr1.y, vr1.z, vr1.w};
    float gm[8] = {gm0.x, gm0.y, gm0.z, gm0.w, gm1.x, gm1.y, gm1.z, gm1.w};
    float bt[8] = {bt0.x, bt0.y, bt0.z, bt0.w, bt1.x, bt1.y, bt1.z, bt1.w};
    float o[8];
    #pragma unroll
    for (int q = 0; q < 8; ++q)
        o[q] = fmaxf((dc * a[q] + bi[q] - mn[q]) * rsqrtf(vr[q] + BN_EPS) * gm[q] + bt[q], 0.0f);
    if (with_res) {
        float4 praw = *(const float4*)(hprev + (size_t)node * HID + fb);
        const __half2* pp = (const __half2*)&praw;
        #pragma unroll
        for (int q = 0; q < 4; ++q) {
            float2 p = __half22float2(pp[q]);
            o[2 * q] += p.x;
            o[2 * q + 1] += p.y;
        }
    }
    half8 ov;
    #pragma unroll
    for (int q = 0; q < 4; ++q)
        ov.h[q] = __floats2half2_rn(o[2 * q], o[2 * q + 1]);
    *(half8*)(hout + (size_t)node * HID + fb) = ov;
}

// ======================= pool (segmented, batch sorted, no atomics) =======================
__device__ __forceinline__ int lower_bound_dev(const int* __restrict__ a, int n, int v) {
    int lo = 0, hi = n;
    while (lo < hi) {
        int m = (lo + hi) >> 1;
        if (a[m] < v) lo = m + 1; else hi = m;
    }
    return lo;
}

__global__ __launch_bounds__(256) void k_pool_seg(const __half* __restrict__ h,
                                                  const int* __restrict__ batch,
                                                  float* __restrict__ gfeat) {
    __shared__ int range[2];
    __shared__ float s[256];
    int g = blockIdx.x, t = threadIdx.x;
    if (t == 0) {
        range[0] = lower_bound_dev(batch, NN, g);
        range[1] = lower_bound_dev(batch, NN, g + 1);
    }
    __syncthreads();
    int start = range[0], end = range[1];
    int f = t & 127, half = t >> 7;
    float acc = 0.0f;
    for (int i = start + half; i < end; i += 2)
        acc += __half2float(h[(size_t)i * HID + f]);
    s[t] = acc;
    __syncthreads();
    if (t < 128) {
        float sum = s[t] + s[t + 128];
        float cnt = (float)(end - start);
        gfeat[(size_t)g * HID + t] = sum / fmaxf(cnt, 1.0f);
    }
}

// ======================= MLP =======================
__global__ void k_mlp0(const float* __restrict__ gfeat,
                       const float* __restrict__ W, const float* __restrict__ b,
                       float* __restrict__ out) {
    __shared__ float srow[HID];
    int g = blockIdx.x, t = threadIdx.x;  // 128 threads
    if (t < HID) srow[t] = gfeat[(size_t)g * HID + t];
    __syncthreads();
    for (int j = t; j < FFN; j += 128) {
        float acc = b[j];
        for (int k = 0; k < HID; ++k) acc += srow[k] * W[k * FFN + j];
        out[(size_t)g * FFN + j] = fmaxf(acc, 0.0f);
    }
}

__global__ void k_mlp1(const float* __restrict__ in, const float* __restrict__ W,
                       const float* __restrict__ b, float* __restrict__ out) {
    __shared__ float srow[FFN];
    int g = blockIdx.x, t = threadIdx.x;  // 128 threads
    for (int k = t; k < FFN; k += 128) srow[k] = in[(size_t)g * FFN + k];
    __syncthreads();
    for (int j = t; j < FFN; j += 128) {
        float acc = b[j];
        for (int k = 0; k < FFN; ++k) acc += srow[k] * W[k * FFN + j];
        out[(size_t)g * FFN + j] = fmaxf(acc, 0.0f);
    }
}

__global__ void k_mlp2(const float* __restrict__ in, const float* __restrict__ W,
                       const float* __restrict__ b, float* __restrict__ out) {
    int g = blockIdx.x, lane = threadIdx.x;  // 64 threads
    float acc = 0.0f;
    for (int k = lane; k < FFN; k += 64) acc += in[(size_t)g * FFN + k] * W[k];
    for (int off = 32; off > 0; off >>= 1) acc += __shfl_down(acc, off);
    if (lane == 0) out[g] = acc + b[0];
}

extern "C" void kernel_launch(void* const* d_in, const int* in_sizes, int n_in,
                              void* d_out, int out_size, void* d_ws, size_t ws_size,
                              hipStream_t stream) {
    const float* x    = (const float*)d_in[0];
    const int*   ei   = (const int*)d_in[1];    // [2,E]: rows then cols
    const int*   batch= (const int*)d_in[2];
    const float* encW = (const float*)d_in[3];
    const float* encb = (const float*)d_in[4];
    const float* Ws   = (const float*)d_in[5];
    const float* bs   = (const float*)d_in[6];
    const float* gam  = (const float*)d_in[7];
    const float* bet  = (const float*)d_in[8];
    const float* mean = (const float*)d_in[9];
    const float* var  = (const float*)d_in[10];
    const float* W0   = (const float*)d_in[11];
    const float* b0   = (const float*)d_in[12];
    const float* W1   = (const float*)d_in[13];
    const float* b1   = (const float*)d_in[14];
    const float* W2   = (const float*)d_in[15];
    const float* b2   = (const float*)d_in[16];
    float* out = (float*)d_out;

    char* w = (char*)d_ws;
    float*  dinv    = (float*)w;  w += alignup((size_t)NN * 4);
    int*    offs    = (int*)w;    w += alignup((size_t)NN * 4);
    int*    ends    = (int*)w;    w += alignup((size_t)NN * 4);
    int*    csr_src = (int*)w;    w += alignup((size_t)NE * 4);
    int*    bcnt    = (int*)w;    w += alignup((size_t)NB * 4);
    int*    bbase   = (int*)w;    w += alignup((size_t)(NB + 1) * 4);
    int*    bcur    = (int*)w;    w += alignup((size_t)NB * CURPAD * 4);
    int*    ebuf    = (int*)w;    w += alignup((size_t)NE * 4);
    __half* hA      = (__half*)w; w += alignup((size_t)NN * HID * 2);
    __half* hB      = (__half*)w; w += alignup((size_t)NN * HID * 2);
    __half* hw_     = (__half*)w; w += alignup((size_t)NN * HID * 2);
    f16*    wt      = (f16*)w;    w += alignup((size_t)NL * HID * HID * 2);
    f16*    wte     = (f16*)w;    w += alignup((size_t)HID * FIN * 2);
    float*  gfeat   = (float*)w;  w += alignup((size_t)NG * HID * 4);
    float*  m0      = (float*)w;  w += alignup((size_t)NG * FFN * 4);
    float*  m1      = (float*)w;  w += alignup((size_t)NG * FFN * 4);

    const int* row = ei;
    const int* col = ei + NE;

    // ---- CSR build (bucketed; all global writes dense; packed ebuf) ----
    hipMemsetAsync(bcnt, 0, (size_t)NB * 4, stream);
    k_bcount<<<256, 1024, 0, stream>>>(col, bcnt);
    k_bscan<<<1, NB, 0, stream>>>(bcnt, bbase, bcur);
    k_bscatter2<<<(NE + 4095) / 4096, 1024, 0, stream>>>(row, col, bcur, ebuf);
    k_binfill<<<NB, 256, 0, stream>>>(ebuf, bbase, offs, ends, dinv, csr_src);

    // ---- weights preconvert + encoder (MFMA) ----
    k_convW<<<64, 256, 0, stream>>>(Ws, encW, wt, wte);
    k_enc_mfma<<<(NN + 63) / 64, 256, 0, stream>>>(x, wte, encb, hA);

    __half* hcur = hA;
    __half* hnext = hB;
    for (int l = 0; l < NL; ++l) {
        k_gemm_mfma<<<(NN + 63) / 64, 256, 0, stream>>>(hcur, wt + (size_t)l * HID * HID, dinv, hw_);
        k_gather<<<(NN * 64 + 255) / 256, 256, 0, stream>>>(
            offs, ends, csr_src, dinv, hw_, hcur,
            bs + l * HID, gam + l * HID, bet + l * HID, mean + l * HID, var + l * HID,
            hnext, l > 0 ? 1 : 0);
        __half* tmp = hcur; hcur = hnext; hnext = tmp;
    }

    // ---- pool + MLP ----
    k_pool_seg<<<NG, 256, 0, stream>>>(hcur, batch, gfeat);
    k_mlp0<<<NG, 128, 0, stream>>>(gfeat, W0, b0, m0);
    k_mlp1<<<NG, 128, 0, stream>>>(m0, W1, b1, m1);
    k_mlp2<<<NG, 64, 0, stream>>>(m1, W2, b2, out);
}

// Round 17
// 492.726 us; speedup vs baseline: 3.2931x; 1.0632x over previous
//
#include <hip/hip_runtime.h>
#include <hip/hip_fp16.h>

#define NN 100000
#define NE 1600000
#define FIN 64
#define HID 128
#define NL 4
#define NG 512
#define FFN 300
#define BN_EPS 1e-5f
#define LDH 136   // padded LDS stride in halves
#define NB 512    // CSR buckets
#define NPB 196   // nodes per bucket; fits 8 bits for packing
#define CURPAD 16 // bucket cursor padding (one per 64B line)
#define CAP 4096  // fixed bucket capacity (mean 3125, sigma ~56 -> 17 sigma headroom)

static inline size_t alignup(size_t x) { return (x + 255) & ~(size_t)255; }

struct half8 { __half2 h[4]; };   // 16 B

typedef _Float16 f16;
typedef __attribute__((ext_vector_type(4))) _Float16 f16x4;
typedef __attribute__((ext_vector_type(8))) _Float16 f16x8;
typedef __attribute__((ext_vector_type(4))) float f32x4;

// ======================= CSR build (fixed-capacity buckets) =======================
__global__ void k_initcur(int* __restrict__ bcur) {
    int t = threadIdx.x;  // NB threads, 1 block
    if (t < NB) bcur[t * CURPAD] = t * CAP;
}

// hierarchical scatter: block histograms 4096 edges in LDS, reserves per-bucket
// ranges with ONE global atomic per bucket per block, then scatters via LDS cursors.
__global__ __launch_bounds__(1024) void k_bscatter2(const int* __restrict__ row,
                                                    const int* __restrict__ col,
                                                    int* __restrict__ bcur,
                                                    int* __restrict__ ebuf) {
    __shared__ int hcnt[NB];
    __shared__ int hbase[NB];
    int t = threadIdx.x;
    int e0 = blockIdx.x * 4096;
    if (t < NB) hcnt[t] = 0;
    __syncthreads();
    #pragma unroll
    for (int k = 0; k < 4; ++k) {
        int e = e0 + k * 1024 + t;
        if (e < NE) atomicAdd(&hcnt[col[e] / NPB], 1);
    }
    __syncthreads();
    if (t < NB) {
        int c = hcnt[t];
        hbase[t] = (c > 0) ? atomicAdd(&bcur[t * CURPAD], c) : 0;
    }
    __syncthreads();
    if (t < NB) hcnt[t] = 0;
    __syncthreads();
    #pragma unroll
    for (int k = 0; k < 4; ++k) {
        int e = e0 + k * 1024 + t;
        if (e < NE) {
            int c = col[e];
            int b = c / NPB;
            int loc = atomicAdd(&hcnt[b], 1);
            ebuf[hbase[b] + loc] = row[e] | ((c - b * NPB) << 17);
        }
    }
}

__global__ __launch_bounds__(256) void k_binfill(const int* __restrict__ ebuf,
                                                 const int* __restrict__ bcur,
                                                 int* __restrict__ offs,
                                                 int* __restrict__ ends,
                                                 float* __restrict__ dinv,
                                                 int* __restrict__ csr_src) {
    __shared__ int cnt[NPB];
    __shared__ int scn[256];
    __shared__ int cur[NPB];
    int b = blockIdx.x, t = threadIdx.x;
    int lo = b * NPB;
    int hi = lo + NPB; if (hi > NN) hi = NN;
    int n = hi - lo;
    if (n <= 0) return;
    int s0 = b * CAP;
    int s1 = bcur[b * CURPAD];   // final cursor after scatter
    for (int i = t; i < NPB; i += 256) cnt[i] = 0;
    __syncthreads();
    for (int j = s0 + t; j < s1; j += 256)
        atomicAdd(&cnt[((unsigned)ebuf[j]) >> 17], 1);
    __syncthreads();
    int v = (t < n) ? cnt[t] : 0;
    scn[t] = v;
    __syncthreads();
    for (int off = 1; off < 256; off <<= 1) {
        int u = (t >= off) ? scn[t - off] : 0;
        __syncthreads();
        scn[t] += u;
        __syncthreads();
    }
    if (t < n) {
        int g = s0 + scn[t] - v;
        offs[lo + t] = g;
        ends[lo + t] = g + v;
        dinv[lo + t] = rsqrtf((float)(v + 1));
        cur[t] = g;
    }
    __syncthreads();
    for (int j = s0 + t; j < s1; j += 256) {
        int e = ebuf[j];
        int pos = atomicAdd(&cur[((unsigned)e) >> 17], 1);
        csr_src[pos] = e & 0x1FFFF;
    }
}

// ==== preconvert: wt[l][c][k]=(f16)Ws[l][k][c]; wte[c][k]=(f16)encW[k][c];
//      folded BN: pscale=gamma*rsqrt(var+eps), pshift=(bias-mean)*pscale+beta ====
__global__ void k_convW(const float* __restrict__ Ws, const float* __restrict__ encW,
                        const float* __restrict__ bs, const float* __restrict__ gam,
                        const float* __restrict__ bet, const float* __restrict__ mean,
                        const float* __restrict__ var,
                        f16* __restrict__ wt, f16* __restrict__ wte,
                        float* __restrict__ pscale, float* __restrict__ pshift) {
    int tid = blockIdx.x * 256 + threadIdx.x;
    for (int i = tid; i < NL * HID * HID; i += 64 * 256) {
        int l = i >> 14, rem = i & 16383;
        int c = rem >> 7, k = rem & 127;
        wt[i] = (f16)Ws[(l << 14) + k * HID + c];
    }
    for (int i = tid; i < HID * FIN; i += 64 * 256) {
        int c = i >> 6, k = i & 63;
        wte[i] = (f16)encW[k * HID + c];
    }
    for (int i = tid; i < NL * HID; i += 64 * 256) {
        float rs = rsqrtf(var[i] + BN_EPS) * gam[i];
        pscale[i] = rs;
        pshift[i] = (bs[i] - mean[i]) * rs + bet[i];
    }
}

// ======== MFMA encoder: h = (x[N,64](f32->f16) @ encW) + b -> f16 ========
__global__ __launch_bounds__(256) void k_enc_mfma(const float* __restrict__ x,
                                                  const f16* __restrict__ wte,
                                                  const float* __restrict__ b,
                                                  __half* __restrict__ h) {
    __shared__ f16 sx[64 * 72];    // 64 rows x 64 k, stride 72
    __shared__ f16 sw[128 * 72];   // 128 cols x 64 k
    int t = threadIdx.x;
    int row0 = blockIdx.x * 64;
    for (int idx = t; idx < 64 * 16; idx += 256) {
        int r = idx >> 4, c4 = (idx & 15) * 4;
        float4 v = {0.0f, 0.0f, 0.0f, 0.0f};
        if (row0 + r < NN) v = *(const float4*)(x + (size_t)(row0 + r) * FIN + c4);
        f16x4 o = {(f16)v.x, (f16)v.y, (f16)v.z, (f16)v.w};
        *(f16x4*)&sx[r * 72 + c4] = o;
    }
    for (int idx = t; idx < 128 * 8; idx += 256) {
        int c = idx >> 3, ch = (idx & 7) * 8;
        *(f16x8*)&sw[c * 72 + ch] = *(const f16x8*)(wte + c * FIN + ch);
    }
    __syncthreads();
    int w = t >> 6, lane = t & 63;
    int lrow = lane & 15, lk = (lane >> 4) * 8;
    f32x4 acc[8];
    #pragma unroll
    for (int ct = 0; ct < 8; ++ct) acc[ct] = (f32x4){0.0f, 0.0f, 0.0f, 0.0f};
    const f16* pa = &sx[(w * 16 + lrow) * 72 + lk];
    #pragma unroll
    for (int ks = 0; ks < 2; ++ks) {
        f16x8 a = *(const f16x8*)(pa + ks * 32);
        #pragma unroll
        for (int ct = 0; ct < 8; ++ct) {
            f16x8 bb = *(const f16x8*)&sw[(ct * 16 + lrow) * 72 + ks * 32 + lk];
            acc[ct] = __builtin_amdgcn_mfma_f32_16x16x32_f16(a, bb, acc[ct], 0, 0, 0);
        }
    }
    float bv[8];
    #pragma unroll
    for (int ct = 0; ct < 8; ++ct) bv[ct] = b[ct * 16 + lrow];
    int rbase = row0 + w * 16 + (lane >> 4) * 4;
    #pragma unroll
    for (int i = 0; i < 4; ++i) {
        int grow = rbase + i;
        if (grow < NN) {
            #pragma unroll
            for (int ct = 0; ct < 8; ++ct)
                h[(size_t)grow * HID + ct * 16 + lrow] = __float2half(acc[ct][i] + bv[ct]);
        }
    }
}

// ==== MFMA layer GEMM: hw = dinv[row] * (h[N,128](f16) @ W[128,128]) -> f16 row-major ====
__global__ __launch_bounds__(256) void k_gemm_mfma(const __half* __restrict__ h,
                                                   const f16* __restrict__ wt,
                                                   const float* __restrict__ dinv,
                                                   __half* __restrict__ hw) {
    __shared__ f16 sh[64 * LDH];
    __shared__ f16 sw[128 * LDH];
    int t = threadIdx.x;
    int row0 = blockIdx.x * 64;
    for (int idx = t; idx < 64 * 16; idx += 256) {
        int r = idx >> 4, ch = (idx & 15) * 8;
        f16x8 v = {0, 0, 0, 0, 0, 0, 0, 0};
        if (row0 + r < NN) v = *(const f16x8*)(h + (size_t)(row0 + r) * HID + ch);
        *(f16x8*)&sh[r * LDH + ch] = v;
    }
    for (int idx = t; idx < 128 * 16; idx += 256) {
        int c = idx >> 4, ch = (idx & 15) * 8;
        *(f16x8*)&sw[c * LDH + ch] = *(const f16x8*)(wt + c * HID + ch);
    }
    __syncthreads();
    int w = t >> 6, lane = t & 63;
    int lrow = lane & 15, lk = (lane >> 4) * 8;
    f32x4 acc[8];
    #pragma unroll
    for (int ct = 0; ct < 8; ++ct) acc[ct] = (f32x4){0.0f, 0.0f, 0.0f, 0.0f};
    const f16* pa = &sh[(w * 16 + lrow) * LDH + lk];
    #pragma unroll
    for (int ks = 0; ks < 4; ++ks) {
        f16x8 a = *(const f16x8*)(pa + ks * 32);
        #pragma unroll
        for (int ct = 0; ct < 8; ++ct) {
            f16x8 b = *(const f16x8*)&sw[(ct * 16 + lrow) * LDH + ks * 32 + lk];
            acc[ct] = __builtin_amdgcn_mfma_f32_16x16x32_f16(a, b, acc[ct], 0, 0, 0);
        }
    }
    int rbase = row0 + w * 16 + (lane >> 4) * 4;
    #pragma unroll
    for (int i = 0; i < 4; ++i) {
        int grow = rbase + i;
        if (grow < NN) {
            float dv = dinv[grow];
            #pragma unroll
            for (int ct = 0; ct < 8; ++ct)
                hw[(size_t)grow * HID + ct * 16 + lrow] = __float2half(dv * acc[ct][i]);
        }
    }
}

// == fused gather: wave per node; 16 lanes x 16B span the 256B row; 4 edge
//    groups; up to 4 loads (16 edges, 64 lines) in flight per wave. Folded-BN epilogue. ==
__device__ __forceinline__ void add8(float* a, float4 raw) {
    const __half2* p = (const __half2*)&raw;
    #pragma unroll
    for (int q = 0; q < 4; ++q) {
        float2 u = __half22float2(p[q]);
        a[2 * q] += u.x;
        a[2 * q + 1] += u.y;
    }
}

__global__ __launch_bounds__(256) void k_gather(
    const int* __restrict__ offs, const int* __restrict__ ends,
    const int* __restrict__ csr_src,
    const float* __restrict__ dinv,
    const __half* __restrict__ hw, const __half* __restrict__ hprev,
    const float* __restrict__ pscale, const float* __restrict__ pshift,
    __half* __restrict__ hout, int with_res) {
    int node = (blockIdx.x * 256 + threadIdx.x) >> 6;
    if (node >= NN) return;
    int lane = threadIdx.x & 63;
    int grp = lane >> 4;      // edge group (4 per wave)
    int fb = (lane & 15) * 8; // first of this lane's 8 features (16 B)
    int s = offs[node], e = ends[node];
    float a[8] = {0, 0, 0, 0, 0, 0, 0, 0};
    int j = s + grp;
    for (; j + 12 < e; j += 16) {  // 4 loads/group -> 16 edges, 64 lines in flight
        int s0 = csr_src[j], s1 = csr_src[j + 4], s2 = csr_src[j + 8], s3 = csr_src[j + 12];
        float4 r0 = *(const float4*)(hw + (size_t)s0 * HID + fb);
        float4 r1 = *(const float4*)(hw + (size_t)s1 * HID + fb);
        float4 r2 = *(const float4*)(hw + (size_t)s2 * HID + fb);
        float4 r3 = *(const float4*)(hw + (size_t)s3 * HID + fb);
        add8(a, r0); add8(a, r1); add8(a, r2); add8(a, r3);
    }
    for (; j + 4 < e; j += 8) {
        int s0 = csr_src[j], s1 = csr_src[j + 4];
        float4 r0 = *(const float4*)(hw + (size_t)s0 * HID + fb);
        float4 r1 = *(const float4*)(hw + (size_t)s1 * HID + fb);
        add8(a, r0); add8(a, r1);
    }
    for (; j < e; j += 4) {
        int s0 = csr_src[j];
        float4 r0 = *(const float4*)(hw + (size_t)s0 * HID + fb);
        add8(a, r0);
    }
    // combine the 4 edge groups
    #pragma unroll
    for (int q = 0; q < 8; ++q) {
        a[q] += __shfl_xor(a[q], 16);
        a[q] += __shfl_xor(a[q], 32);
    }
    if (grp) return;
    // self-loop (pre-scaled row) then final dinv[c] scale + folded BN + ReLU (+res)
    float4 sraw = *(const float4*)(hw + (size_t)node * HID + fb);
    add8(a, sraw);
    float dc = dinv[node];
    float4 ps0 = *(const float4*)(pscale + fb), ps1 = *(const float4*)(pscale + fb + 4);
    float4 pf0 = *(const float4*)(pshift + fb), pf1 = *(const float4*)(pshift + fb + 4);
    float ps[8] = {ps0.x, ps0.y, ps0.z, ps0.w, ps1.x, ps1.y, ps1.z, ps1.w};
    float pf[8] = {pf0.x, pf0.y, pf0.z, pf0.w, pf1.x, pf1.y, pf1.z, pf1.w};
    float o[8];
    #pragma unroll
    for (int q = 0; q < 8; ++q)
        o[q] = fmaxf(dc * a[q] * ps[q] + pf[q], 0.0f);
    if (with_res) {
        float4 praw = *(const float4*)(hprev + (size_t)node * HID + fb);
        const __half2* pp = (const __half2*)&praw;
        #pragma unroll
        for (int q = 0; q < 4; ++q) {
            float2 p = __half22float2(pp[q]);
            o[2 * q] += p.x;
            o[2 * q + 1] += p.y;
        }
    }
    half8 ov;
    #pragma unroll
    for (int q = 0; q < 4; ++q)
        ov.h[q] = __floats2half2_rn(o[2 * q], o[2 * q + 1]);
    *(half8*)(hout + (size_t)node * HID + fb) = ov;
}

// ======================= pool (segmented, batch sorted, no atomics) =======================
__device__ __forceinline__ int lower_bound_dev(const int* __restrict__ a, int n, int v) {
    int lo = 0, hi = n;
    while (lo < hi) {
        int m = (lo + hi) >> 1;
        if (a[m] < v) lo = m + 1; else hi = m;
    }
    return lo;
}

__global__ __launch_bounds__(256) void k_pool_seg(const __half* __restrict__ h,
                                                  const int* __restrict__ batch,
                                                  float* __restrict__ gfeat) {
    __shared__ int range[2];
    __shared__ float s[256];
    int g = blockIdx.x, t = threadIdx.x;
    if (t == 0) {
        range[0] = lower_bound_dev(batch, NN, g);
        range[1] = lower_bound_dev(batch, NN, g + 1);
    }
    __syncthreads();
    int start = range[0], end = range[1];
    int f = t & 127, half = t >> 7;
    float acc = 0.0f;
    for (int i = start + half; i < end; i += 2)
        acc += __half2float(h[(size_t)i * HID + f]);
    s[t] = acc;
    __syncthreads();
    if (t < 128) {
        float sum = s[t] + s[t + 128];
        float cnt = (float)(end - start);
        gfeat[(size_t)g * HID + t] = sum / fmaxf(cnt, 1.0f);
    }
}

// ======================= MLP =======================
__global__ void k_mlp0(const float* __restrict__ gfeat,
                       const float* __restrict__ W, const float* __restrict__ b,
                       float* __restrict__ out) {
    __shared__ float srow[HID];
    int g = blockIdx.x, t = threadIdx.x;  // 128 threads
    if (t < HID) srow[t] = gfeat[(size_t)g * HID + t];
    __syncthreads();
    for (int j = t; j < FFN; j += 128) {
        float acc = b[j];
        for (int k = 0; k < HID; ++k) acc += srow[k] * W[k * FFN + j];
        out[(size_t)g * FFN + j] = fmaxf(acc, 0.0f);
    }
}

__global__ void k_mlp1(const float* __restrict__ in, const float* __restrict__ W,
                       const float* __restrict__ b, float* __restrict__ out) {
    __shared__ float srow[FFN];
    int g = blockIdx.x, t = threadIdx.x;  // 128 threads
    for (int k = t; k < FFN; k += 128) srow[k] = in[(size_t)g * FFN + k];
    __syncthreads();
    for (int j = t; j < FFN; j += 128) {
        float acc = b[j];
        for (int k = 0; k < FFN; ++k) acc += srow[k] * W[k * FFN + j];
        out[(size_t)g * FFN + j] = fmaxf(acc, 0.0f);
    }
}

__global__ void k_mlp2(const float* __restrict__ in, const float* __restrict__ W,
                       const float* __restrict__ b, float* __restrict__ out) {
    int g = blockIdx.x, lane = threadIdx.x;  // 64 threads
    float acc = 0.0f;
    for (int k = lane; k < FFN; k += 64) acc += in[(size_t)g * FFN + k] * W[k];
    for (int off = 32; off > 0; off >>= 1) acc += __shfl_down(acc, off);
    if (lane == 0) out[g] = acc + b[0];
}

extern "C" void kernel_launch(void* const* d_in, const int* in_sizes, int n_in,
                              void* d_out, int out_size, void* d_ws, size_t ws_size,
                              hipStream_t stream) {
    const float* x    = (const float*)d_in[0];
    const int*   ei   = (const int*)d_in[1];    // [2,E]: rows then cols
    const int*   batch= (const int*)d_in[2];
    const float* encW = (const float*)d_in[3];
    const float* encb = (const float*)d_in[4];
    const float* Ws   = (const float*)d_in[5];
    const float* bs   = (const float*)d_in[6];
    const float* gam  = (const float*)d_in[7];
    const float* bet  = (const float*)d_in[8];
    const float* mean = (const float*)d_in[9];
    const float* var  = (const float*)d_in[10];
    const float* W0   = (const float*)d_in[11];
    const float* b0   = (const float*)d_in[12];
    const float* W1   = (const float*)d_in[13];
    const float* b1   = (const float*)d_in[14];
    const float* W2   = (const float*)d_in[15];
    const float* b2   = (const float*)d_in[16];
    float* out = (float*)d_out;

    char* w = (char*)d_ws;
    float*  dinv    = (float*)w;  w += alignup((size_t)NN * 4);
    int*    offs    = (int*)w;    w += alignup((size_t)NN * 4);
    int*    ends    = (int*)w;    w += alignup((size_t)NN * 4);
    int*    csr_src = (int*)w;    w += alignup((size_t)NB * CAP * 4);
    int*    bcur    = (int*)w;    w += alignup((size_t)NB * CURPAD * 4);
    int*    ebuf    = (int*)w;    w += alignup((size_t)NB * CAP * 4);
    __half* hA      = (__half*)w; w += alignup((size_t)NN * HID * 2);
    __half* hB      = (__half*)w; w += alignup((size_t)NN * HID * 2);
    __half* hw_     = (__half*)w; w += alignup((size_t)NN * HID * 2);
    f16*    wt      = (f16*)w;    w += alignup((size_t)NL * HID * HID * 2);
    f16*    wte     = (f16*)w;    w += alignup((size_t)HID * FIN * 2);
    float*  pscale  = (float*)w;  w += alignup((size_t)NL * HID * 4);
    float*  pshift  = (float*)w;  w += alignup((size_t)NL * HID * 4);
    float*  gfeat   = (float*)w;  w += alignup((size_t)NG * HID * 4);
    float*  m0      = (float*)w;  w += alignup((size_t)NG * FFN * 4);
    float*  m1      = (float*)w;  w += alignup((size_t)NG * FFN * 4);

    const int* row = ei;
    const int* col = ei + NE;

    // ---- CSR build (fixed-capacity buckets: no count pass, no scan) ----
    k_initcur<<<1, NB, 0, stream>>>(bcur);
    k_bscatter2<<<(NE + 4095) / 4096, 1024, 0, stream>>>(row, col, bcur, ebuf);
    k_binfill<<<NB, 256, 0, stream>>>(ebuf, bcur, offs, ends, dinv, csr_src);

    // ---- weights preconvert (incl. folded BN) + encoder (MFMA) ----
    k_convW<<<64, 256, 0, stream>>>(Ws, encW, bs, gam, bet, mean, var,
                                    wt, wte, pscale, pshift);
    k_enc_mfma<<<(NN + 63) / 64, 256, 0, stream>>>(x, wte, encb, hA);

    __half* hcur = hA;
    __half* hnext = hB;
    for (int l = 0; l < NL; ++l) {
        k_gemm_mfma<<<(NN + 63) / 64, 256, 0, stream>>>(hcur, wt + (size_t)l * HID * HID, dinv, hw_);
        k_gather<<<(NN * 64 + 255) / 256, 256, 0, stream>>>(
            offs, ends, csr_src, dinv, hw_, hcur,
            pscale + l * HID, pshift + l * HID,
            hnext, l > 0 ? 1 : 0);
        __half* tmp = hcur; hcur = hnext; hnext = tmp;
    }

    // ---- pool + MLP ----
    k_pool_seg<<<NG, 256, 0, stream>>>(hcur, batch, gfeat);
    k_mlp0<<<NG, 128, 0, stream>>>(gfeat, W0, b0, m0);
    k_mlp1<<<NG, 128, 0, stream>>>(m0, W1, b1, m1);
    k_mlp2<<<NG, 64, 0, stream>>>(m1, W2, b2, out);
}

// Round 18
// 482.041 us; speedup vs baseline: 3.3661x; 1.0222x over previous
//
#include <hip/hip_runtime.h>
#include <hip/hip_fp16.h>

#define NN 100000
#define NE 1600000
#define FIN 64
#define HID 128
#define NL 4
#define NG 512
#define FFN 300
#define BN_EPS 1e-5f
#define LDH 136   // padded LDS stride in halves
#define NB 512    // CSR buckets
#define NPB 196   // nodes per bucket; fits 8 bits for packing
#define CURPAD 16 // bucket cursor padding (one per 64B line)
#define CAP 4096  // fixed bucket capacity (mean 3125, sigma ~56 -> 17 sigma headroom)

static inline size_t alignup(size_t x) { return (x + 255) & ~(size_t)255; }

struct half8 { __half2 h[4]; };   // 16 B

typedef _Float16 f16;
typedef __attribute__((ext_vector_type(4))) _Float16 f16x4;
typedef __attribute__((ext_vector_type(8))) _Float16 f16x8;
typedef __attribute__((ext_vector_type(4))) float f32x4;

// ======================= CSR build (fixed-capacity buckets) =======================
// hierarchical scatter: block histograms 4096 edges in LDS, reserves per-bucket
// ranges with ONE global atomic per bucket per block, then scatters via LDS cursors.
__global__ __launch_bounds__(1024) void k_bscatter2(const int* __restrict__ row,
                                                    const int* __restrict__ col,
                                                    int* __restrict__ bcur,
                                                    int* __restrict__ ebuf) {
    __shared__ int hcnt[NB];
    __shared__ int hbase[NB];
    int t = threadIdx.x;
    int e0 = blockIdx.x * 4096;
    if (t < NB) hcnt[t] = 0;
    __syncthreads();
    #pragma unroll
    for (int k = 0; k < 4; ++k) {
        int e = e0 + k * 1024 + t;
        if (e < NE) atomicAdd(&hcnt[col[e] / NPB], 1);
    }
    __syncthreads();
    if (t < NB) {
        int c = hcnt[t];
        hbase[t] = (c > 0) ? atomicAdd(&bcur[t * CURPAD], c) : 0;
    }
    __syncthreads();
    if (t < NB) hcnt[t] = 0;
    __syncthreads();
    #pragma unroll
    for (int k = 0; k < 4; ++k) {
        int e = e0 + k * 1024 + t;
        if (e < NE) {
            int c = col[e];
            int b = c / NPB;
            int loc = atomicAdd(&hcnt[b], 1);
            ebuf[hbase[b] + loc] = row[e] | ((c - b * NPB) << 17);
        }
    }
}

__global__ __launch_bounds__(256) void k_binfill(const int* __restrict__ ebuf,
                                                 const int* __restrict__ bcur,
                                                 int* __restrict__ offs,
                                                 int* __restrict__ ends,
                                                 float* __restrict__ dinv,
                                                 int* __restrict__ csr_src) {
    __shared__ int cnt[NPB];
    __shared__ int scn[256];
    __shared__ int cur[NPB];
    int b = blockIdx.x, t = threadIdx.x;
    int lo = b * NPB;
    int hi = lo + NPB; if (hi > NN) hi = NN;
    int n = hi - lo;
    if (n <= 0) return;
    int s0 = b * CAP;
    int s1 = bcur[b * CURPAD];   // final cursor after scatter
    for (int i = t; i < NPB; i += 256) cnt[i] = 0;
    __syncthreads();
    for (int j = s0 + t; j < s1; j += 256)
        atomicAdd(&cnt[((unsigned)ebuf[j]) >> 17], 1);
    __syncthreads();
    int v = (t < n) ? cnt[t] : 0;
    scn[t] = v;
    __syncthreads();
    for (int off = 1; off < 256; off <<= 1) {
        int u = (t >= off) ? scn[t - off] : 0;
        __syncthreads();
        scn[t] += u;
        __syncthreads();
    }
    if (t < n) {
        int g = s0 + scn[t] - v;
        offs[lo + t] = g;
        ends[lo + t] = g + v;
        dinv[lo + t] = rsqrtf((float)(v + 1));
        cur[t] = g;
    }
    __syncthreads();
    for (int j = s0 + t; j < s1; j += 256) {
        int e = ebuf[j];
        int pos = atomicAdd(&cur[((unsigned)e) >> 17], 1);
        csr_src[pos] = e & 0x1FFFF;
    }
}

// ==== preconvert + cursor init: wt[l][c][k]=(f16)Ws[l][k][c]; wte[c][k]=(f16)encW[k][c];
//      folded BN: pscale=gamma*rsqrt(var+eps), pshift=(bias-mean)*pscale+beta ====
__global__ void k_convW(const float* __restrict__ Ws, const float* __restrict__ encW,
                        const float* __restrict__ bs, const float* __restrict__ gam,
                        const float* __restrict__ bet, const float* __restrict__ mean,
                        const float* __restrict__ var,
                        f16* __restrict__ wt, f16* __restrict__ wte,
                        float* __restrict__ pscale, float* __restrict__ pshift,
                        int* __restrict__ bcur) {
    int tid = blockIdx.x * 256 + threadIdx.x;
    if (tid < NB) bcur[tid * CURPAD] = tid * CAP;
    for (int i = tid; i < NL * HID * HID; i += 64 * 256) {
        int l = i >> 14, rem = i & 16383;
        int c = rem >> 7, k = rem & 127;
        wt[i] = (f16)Ws[(l << 14) + k * HID + c];
    }
    for (int i = tid; i < HID * FIN; i += 64 * 256) {
        int c = i >> 6, k = i & 63;
        wte[i] = (f16)encW[k * HID + c];
    }
    for (int i = tid; i < NL * HID; i += 64 * 256) {
        float rs = rsqrtf(var[i] + BN_EPS) * gam[i];
        pscale[i] = rs;
        pshift[i] = (bs[i] - mean[i]) * rs + bet[i];
    }
}

// ======== fused MFMA encoder + layer-0 GEMM:
//   stage1: h = (x[N,64] @ encW) + be  -> LDS (f16)
//   stage2: hw = dinv[row] * (h @ W0)  -> global f16 ========
__global__ __launch_bounds__(256) void k_encgemm(const float* __restrict__ x,
                                                 const f16* __restrict__ wte,
                                                 const float* __restrict__ be,
                                                 const f16* __restrict__ wt0,
                                                 const float* __restrict__ dinv,
                                                 __half* __restrict__ hw) {
    __shared__ f16 sx[64 * 72];     // x tile (f16), 9.2 KB
    __shared__ f16 swe[128 * 72];   // enc weights, 18.4 KB
    __shared__ f16 sh[64 * LDH];    // intermediate h tile, 17.4 KB
    __shared__ f16 sw0[128 * LDH];  // layer-0 weights, 34.8 KB
    int t = threadIdx.x;
    int row0 = blockIdx.x * 64;
    for (int idx = t; idx < 64 * 16; idx += 256) {
        int r = idx >> 4, c4 = (idx & 15) * 4;
        float4 v = {0.0f, 0.0f, 0.0f, 0.0f};
        if (row0 + r < NN) v = *(const float4*)(x + (size_t)(row0 + r) * FIN + c4);
        f16x4 o = {(f16)v.x, (f16)v.y, (f16)v.z, (f16)v.w};
        *(f16x4*)&sx[r * 72 + c4] = o;
    }
    for (int idx = t; idx < 128 * 8; idx += 256) {
        int c = idx >> 3, ch = (idx & 7) * 8;
        *(f16x8*)&swe[c * 72 + ch] = *(const f16x8*)(wte + c * FIN + ch);
    }
    for (int idx = t; idx < 128 * 16; idx += 256) {
        int c = idx >> 4, ch = (idx & 15) * 8;
        *(f16x8*)&sw0[c * LDH + ch] = *(const f16x8*)(wt0 + c * HID + ch);
    }
    __syncthreads();
    int w = t >> 6, lane = t & 63;
    int lrow = lane & 15, lk = (lane >> 4) * 8;
    // ---- stage 1: enc ----
    f32x4 acc[8];
    #pragma unroll
    for (int ct = 0; ct < 8; ++ct) acc[ct] = (f32x4){0.0f, 0.0f, 0.0f, 0.0f};
    {
        const f16* pa = &sx[(w * 16 + lrow) * 72 + lk];
        #pragma unroll
        for (int ks = 0; ks < 2; ++ks) {
            f16x8 a = *(const f16x8*)(pa + ks * 32);
            #pragma unroll
            for (int ct = 0; ct < 8; ++ct) {
                f16x8 bb = *(const f16x8*)&swe[(ct * 16 + lrow) * 72 + ks * 32 + lk];
                acc[ct] = __builtin_amdgcn_mfma_f32_16x16x32_f16(a, bb, acc[ct], 0, 0, 0);
            }
        }
    }
    float bv[8];
    #pragma unroll
    for (int ct = 0; ct < 8; ++ct) bv[ct] = be[ct * 16 + lrow];
    int lr4 = w * 16 + (lane >> 4) * 4;
    #pragma unroll
    for (int i = 0; i < 4; ++i)
        #pragma unroll
        for (int ct = 0; ct < 8; ++ct)
            sh[(lr4 + i) * LDH + ct * 16 + lrow] = (f16)(acc[ct][i] + bv[ct]);
    __syncthreads();
    // ---- stage 2: gemm layer 0 ----
    #pragma unroll
    for (int ct = 0; ct < 8; ++ct) acc[ct] = (f32x4){0.0f, 0.0f, 0.0f, 0.0f};
    {
        const f16* pa = &sh[(w * 16 + lrow) * LDH + lk];
        #pragma unroll
        for (int ks = 0; ks < 4; ++ks) {
            f16x8 a = *(const f16x8*)(pa + ks * 32);
            #pragma unroll
            for (int ct = 0; ct < 8; ++ct) {
                f16x8 b = *(const f16x8*)&sw0[(ct * 16 + lrow) * LDH + ks * 32 + lk];
                acc[ct] = __builtin_amdgcn_mfma_f32_16x16x32_f16(a, b, acc[ct], 0, 0, 0);
            }
        }
    }
    int rbase = row0 + lr4;
    #pragma unroll
    for (int i = 0; i < 4; ++i) {
        int grow = rbase + i;
        if (grow < NN) {
            float dv = dinv[grow];
            #pragma unroll
            for (int ct = 0; ct < 8; ++ct)
                hw[(size_t)grow * HID + ct * 16 + lrow] = __float2half(dv * acc[ct][i]);
        }
    }
}

// ==== MFMA layer GEMM: hw = dinv[row] * (h[N,128](f16) @ W[128,128]) -> f16 row-major ====
__global__ __launch_bounds__(256) void k_gemm_mfma(const __half* __restrict__ h,
                                                   const f16* __restrict__ wt,
                                                   const float* __restrict__ dinv,
                                                   __half* __restrict__ hw) {
    __shared__ f16 sh[64 * LDH];
    __shared__ f16 sw[128 * LDH];
    int t = threadIdx.x;
    int row0 = blockIdx.x * 64;
    for (int idx = t; idx < 64 * 16; idx += 256) {
        int r = idx >> 4, ch = (idx & 15) * 8;
        f16x8 v = {0, 0, 0, 0, 0, 0, 0, 0};
        if (row0 + r < NN) v = *(const f16x8*)(h + (size_t)(row0 + r) * HID + ch);
        *(f16x8*)&sh[r * LDH + ch] = v;
    }
    for (int idx = t; idx < 128 * 16; idx += 256) {
        int c = idx >> 4, ch = (idx & 15) * 8;
        *(f16x8*)&sw[c * LDH + ch] = *(const f16x8*)(wt + c * HID + ch);
    }
    __syncthreads();
    int w = t >> 6, lane = t & 63;
    int lrow = lane & 15, lk = (lane >> 4) * 8;
    f32x4 acc[8];
    #pragma unroll
    for (int ct = 0; ct < 8; ++ct) acc[ct] = (f32x4){0.0f, 0.0f, 0.0f, 0.0f};
    const f16* pa = &sh[(w * 16 + lrow) * LDH + lk];
    #pragma unroll
    for (int ks = 0; ks < 4; ++ks) {
        f16x8 a = *(const f16x8*)(pa + ks * 32);
        #pragma unroll
        for (int ct = 0; ct < 8; ++ct) {
            f16x8 b = *(const f16x8*)&sw[(ct * 16 + lrow) * LDH + ks * 32 + lk];
            acc[ct] = __builtin_amdgcn_mfma_f32_16x16x32_f16(a, b, acc[ct], 0, 0, 0);
        }
    }
    int rbase = row0 + w * 16 + (lane >> 4) * 4;
    #pragma unroll
    for (int i = 0; i < 4; ++i) {
        int grow = rbase + i;
        if (grow < NN) {
            float dv = dinv[grow];
            #pragma unroll
            for (int ct = 0; ct < 8; ++ct)
                hw[(size_t)grow * HID + ct * 16 + lrow] = __float2half(dv * acc[ct][i]);
        }
    }
}

// == fused gather: wave per node; 16 lanes x 16B span the 256B row; 4 edge
//    groups; up to 4 loads (16 edges, 64 lines) in flight per wave. Folded-BN epilogue. ==
__device__ __forceinline__ void add8(float* a, float4 raw) {
    const __half2* p = (const __half2*)&raw;
    #pragma unroll
    for (int q = 0; q < 4; ++q) {
        float2 u = __half22float2(p[q]);
        a[2 * q] += u.x;
        a[2 * q + 1] += u.y;
    }
}

__global__ __launch_bounds__(256) void k_gather(
    const int* __restrict__ offs, const int* __restrict__ ends,
    const int* __restrict__ csr_src,
    const float* __restrict__ dinv,
    const __half* __restrict__ hw, const __half* __restrict__ hprev,
    const float* __restrict__ pscale, const float* __restrict__ pshift,
    __half* __restrict__ hout, int with_res) {
    int node = (blockIdx.x * 256 + threadIdx.x) >> 6;
    if (node >= NN) return;
    int lane = threadIdx.x & 63;
    int grp = lane >> 4;      // edge group (4 per wave)
    int fb = (lane & 15) * 8; // first of this lane's 8 features (16 B)
    int s = offs[node], e = ends[node];
    float a[8] = {0, 0, 0, 0, 0, 0, 0, 0};
    int j = s + grp;
    for (; j + 12 < e; j += 16) {  // 4 loads/group -> 16 edges, 64 lines in flight
        int s0 = csr_src[j], s1 = csr_src[j + 4], s2 = csr_src[j + 8], s3 = csr_src[j + 12];
        float4 r0 = *(const float4*)(hw + (size_t)s0 * HID + fb);
        float4 r1 = *(const float4*)(hw + (size_t)s1 * HID + fb);
        float4 r2 = *(const float4*)(hw + (size_t)s2 * HID + fb);
        float4 r3 = *(const float4*)(hw + (size_t)s3 * HID + fb);
        add8(a, r0); add8(a, r1); add8(a, r2); add8(a, r3);
    }
    for (; j + 4 < e; j += 8) {
        int s0 = csr_src[j], s1 = csr_src[j + 4];
        float4 r0 = *(const float4*)(hw + (size_t)s0 * HID + fb);
        float4 r1 = *(const float4*)(hw + (size_t)s1 * HID + fb);
        add8(a, r0); add8(a, r1);
    }
    for (; j < e; j += 4) {
        int s0 = csr_src[j];
        float4 r0 = *(const float4*)(hw + (size_t)s0 * HID + fb);
        add8(a, r0);
    }
    // combine the 4 edge groups
    #pragma unroll
    for (int q = 0; q < 8; ++q) {
        a[q] += __shfl_xor(a[q], 16);
        a[q] += __shfl_xor(a[q], 32);
    }
    if (grp) return;
    // self-loop (pre-scaled row) then final dinv[c] scale + folded BN + ReLU (+res)
    float4 sraw = *(const float4*)(hw + (size_t)node * HID + fb);
    add8(a, sraw);
    float dc = dinv[node];
    float4 ps0 = *(const float4*)(pscale + fb), ps1 = *(const float4*)(pscale + fb + 4);
    float4 pf0 = *(const float4*)(pshift + fb), pf1 = *(const float4*)(pshift + fb + 4);
    float ps[8] = {ps0.x, ps0.y, ps0.z, ps0.w, ps1.x, ps1.y, ps1.z, ps1.w};
    float pf[8] = {pf0.x, pf0.y, pf0.z, pf0.w, pf1.x, pf1.y, pf1.z, pf1.w};
    float o[8];
    #pragma unroll
    for (int q = 0; q < 8; ++q)
        o[q] = fmaxf(dc * a[q] * ps[q] + pf[q], 0.0f);
    if (with_res) {
        float4 praw = *(const float4*)(hprev + (size_t)node * HID + fb);
        const __half2* pp = (const __half2*)&praw;
        #pragma unroll
        for (int q = 0; q < 4; ++q) {
            float2 p = __half22float2(pp[q]);
            o[2 * q] += p.x;
            o[2 * q + 1] += p.y;
        }
    }
    half8 ov;
    #pragma unroll
    for (int q = 0; q < 4; ++q)
        ov.h[q] = __floats2half2_rn(o[2 * q], o[2 * q + 1]);
    *(half8*)(hout + (size_t)node * HID + fb) = ov;
}

// ======================= pool (segmented, batch sorted, no atomics) =======================
__device__ __forceinline__ int lower_bound_dev(const int* __restrict__ a, int n, int v) {
    int lo = 0, hi = n;
    while (lo < hi) {
        int m = (lo + hi) >> 1;
        if (a[m] < v) lo = m + 1; else hi = m;
    }
    return lo;
}

__global__ __launch_bounds__(256) void k_pool_seg(const __half* __restrict__ h,
                                                  const int* __restrict__ batch,
                                                  float* __restrict__ gfeat) {
    __shared__ int range[2];
    __shared__ float s[256];
    int g = blockIdx.x, t = threadIdx.x;
    if (t == 0) {
        range[0] = lower_bound_dev(batch, NN, g);
        range[1] = lower_bound_dev(batch, NN, g + 1);
    }
    __syncthreads();
    int start = range[0], end = range[1];
    int f = t & 127, half = t >> 7;
    float acc = 0.0f;
    for (int i = start + half; i < end; i += 2)
        acc += __half2float(h[(size_t)i * HID + f]);
    s[t] = acc;
    __syncthreads();
    if (t < 128) {
        float sum = s[t] + s[t + 128];
        float cnt = (float)(end - start);
        gfeat[(size_t)g * HID + t] = sum / fmaxf(cnt, 1.0f);
    }
}

// ======================= MLP =======================
__global__ void k_mlp0(const float* __restrict__ gfeat,
                       const float* __restrict__ W, const float* __restrict__ b,
                       float* __restrict__ out) {
    __shared__ float srow[HID];
    int g = blockIdx.x, t = threadIdx.x;  // 128 threads
    if (t < HID) srow[t] = gfeat[(size_t)g * HID + t];
    __syncthreads();
    for (int j = t; j < FFN; j += 128) {
        float acc = b[j];
        for (int k = 0; k < HID; ++k) acc += srow[k] * W[k * FFN + j];
        out[(size_t)g * FFN + j] = fmaxf(acc, 0.0f);
    }
}

// fused mlp1 + mlp2: m1 never leaves LDS
__global__ void k_mlp12(const float* __restrict__ in, const float* __restrict__ W1,
                        const float* __restrict__ b1, const float* __restrict__ W2,
                        const float* __restrict__ b2, float* __restrict__ out) {
    __shared__ float srow[FFN];
    __shared__ float s2[FFN];
    __shared__ float red[128];
    int g = blockIdx.x, t = threadIdx.x;  // 128 threads
    for (int k = t; k < FFN; k += 128) srow[k] = in[(size_t)g * FFN + k];
    __syncthreads();
    for (int j = t; j < FFN; j += 128) {
        float acc = b1[j];
        for (int k = 0; k < FFN; ++k) acc += srow[k] * W1[k * FFN + j];
        s2[j] = fmaxf(acc, 0.0f);
    }
    __syncthreads();
    float partial = 0.0f;
    for (int k = t; k < FFN; k += 128) partial += s2[k] * W2[k];
    red[t] = partial;
    __syncthreads();
    for (int off = 64; off > 0; off >>= 1) {
        if (t < off) red[t] += red[t + off];
        __syncthreads();
    }
    if (t == 0) out[g] = red[0] + b2[0];
}

extern "C" void kernel_launch(void* const* d_in, const int* in_sizes, int n_in,
                              void* d_out, int out_size, void* d_ws, size_t ws_size,
                              hipStream_t stream) {
    const float* x    = (const float*)d_in[0];
    const int*   ei   = (const int*)d_in[1];    // [2,E]: rows then cols
    const int*   batch= (const int*)d_in[2];
    const float* encW = (const float*)d_in[3];
    const float* encb = (const float*)d_in[4];
    const float* Ws   = (const float*)d_in[5];
    const float* bs   = (const float*)d_in[6];
    const float* gam  = (const float*)d_in[7];
    const float* bet  = (const float*)d_in[8];
    const float* mean = (const float*)d_in[9];
    const float* var  = (const float*)d_in[10];
    const float* W0   = (const float*)d_in[11];
    const float* b0   = (const float*)d_in[12];
    const float* W1   = (const float*)d_in[13];
    const float* b1   = (const float*)d_in[14];
    const float* W2   = (const float*)d_in[15];
    const float* b2   = (const float*)d_in[16];
    float* out = (float*)d_out;

    char* w = (char*)d_ws;
    float*  dinv    = (float*)w;  w += alignup((size_t)NN * 4);
    int*    offs    = (int*)w;    w += alignup((size_t)NN * 4);
    int*    ends    = (int*)w;    w += alignup((size_t)NN * 4);
    int*    csr_src = (int*)w;    w += alignup((size_t)NB * CAP * 4);
    int*    bcur    = (int*)w;    w += alignup((size_t)NB * CURPAD * 4);
    int*    ebuf    = (int*)w;    w += alignup((size_t)NB * CAP * 4);
    __half* hA      = (__half*)w; w += alignup((size_t)NN * HID * 2);
    __half* hB      = (__half*)w; w += alignup((size_t)NN * HID * 2);
    __half* hw_     = (__half*)w; w += alignup((size_t)NN * HID * 2);
    f16*    wt      = (f16*)w;    w += alignup((size_t)NL * HID * HID * 2);
    f16*    wte     = (f16*)w;    w += alignup((size_t)HID * FIN * 2);
    float*  pscale  = (float*)w;  w += alignup((size_t)NL * HID * 4);
    float*  pshift  = (float*)w;  w += alignup((size_t)NL * HID * 4);
    float*  gfeat   = (float*)w;  w += alignup((size_t)NG * HID * 4);
    float*  m0      = (float*)w;  w += alignup((size_t)NG * FFN * 4);

    const int* row = ei;
    const int* col = ei + NE;

    // ---- preconvert weights + init cursors (independent of CSR) ----
    k_convW<<<64, 256, 0, stream>>>(Ws, encW, bs, gam, bet, mean, var,
                                    wt, wte, pscale, pshift, bcur);

    // ---- CSR build (fixed-capacity buckets) ----
    k_bscatter2<<<(NE + 4095) / 4096, 1024, 0, stream>>>(row, col, bcur, ebuf);
    k_binfill<<<NB, 256, 0, stream>>>(ebuf, bcur, offs, ends, dinv, csr_src);

    // ---- fused encoder + layer-0 GEMM ----
    k_encgemm<<<(NN + 63) / 64, 256, 0, stream>>>(x, wte, encb, wt, dinv, hw_);

    // ---- layer 0 gather, then layers 1..3 ----
    __half* hcur = hA;   // will hold gather-0 output
    __half* hnext = hB;
    k_gather<<<(NN * 64 + 255) / 256, 256, 0, stream>>>(
        offs, ends, csr_src, dinv, hw_, hcur /*unused: with_res=0*/,
        pscale, pshift, hcur, 0);
    for (int l = 1; l < NL; ++l) {
        k_gemm_mfma<<<(NN + 63) / 64, 256, 0, stream>>>(hcur, wt + (size_t)l * HID * HID, dinv, hw_);
        k_gather<<<(NN * 64 + 255) / 256, 256, 0, stream>>>(
            offs, ends, csr_src, dinv, hw_, hcur,
            pscale + l * HID, pshift + l * HID,
            hnext, 1);
        __half* tmp = hcur; hcur = hnext; hnext = tmp;
    }

    // ---- pool + MLP ----
    k_pool_seg<<<NG, 256, 0, stream>>>(hcur, batch, gfeat);
    k_mlp0<<<NG, 128, 0, stream>>>(gfeat, W0, b0, m0);
    k_mlp12<<<NG, 128, 0, stream>>>(m0, W1, b1, W2, b2, out);
}